// Round 1
// baseline (712.521 us; speedup 1.0000x reference)
//
#include <hip/hip_runtime.h>
#include <stdint.h>

// ---------------------------------------------------------------------------
// Binary (sign) weight 3-layer MLP:
//   h1 = relu(x[65536,784] @ sign(W1)^T[784,1000] + b1)   -> bf16 [65536,1024] (pad)
//   h2 = relu(h1 @ sign(W2)^T + b2)                        -> bf16 [65536,512] (pad)
//   out = h2 @ sign(W3)^T + b3                             -> f32  [65536,10]
// Strategy: binarize weights to bf16 +/-1 with zero padding, then m97-style
// MFMA GEMMs (128x128 tile, BK=32, 16x16x32_bf16, global_load_lds width 16).
// ---------------------------------------------------------------------------

typedef __attribute__((ext_vector_type(8))) short bf16x8;
typedef __attribute__((ext_vector_type(4))) float f32x4;

typedef const __attribute__((address_space(1))) unsigned int* as1_u32p;
typedef __attribute__((address_space(3))) unsigned int* as3_u32p;

__device__ __forceinline__ void glds16(const void* g, void* l) {
  // async global->LDS, 16B per lane; LDS dest = wave-uniform base + lane*16
  __builtin_amdgcn_global_load_lds((as1_u32p)g, (as3_u32p)l, 16, 0, 0);
}

__device__ __forceinline__ unsigned short f2bf(float f) {
  union { float f; unsigned u; } c;
  c.f = f;
  unsigned u = c.u;
  u += 0x7FFFu + ((u >> 16) & 1u);  // RTNE
  return (unsigned short)(u >> 16);
}

// ---------------------------------------------------------------------------
// Binarize + zero-pad weights: dst[n,k] = (n<Ns && k<Ks) ? sign(src[n,k]) : 0
// stored as bf16 (+1 = 0x3F80, -1 = 0xBF80)
// ---------------------------------------------------------------------------
__global__ void binarize_kernel(const float* __restrict__ src, int Ns, int Ks,
                                short* __restrict__ dst, int Np, int Kp) {
  int idx = blockIdx.x * 256 + threadIdx.x;
  if (idx >= Np * Kp) return;
  int n = idx / Kp;
  int k = idx - n * Kp;
  short v = 0;
  if (n < Ns && k < Ks)
    v = (src[n * Ks + k] >= 0.0f) ? (short)0x3F80 : (short)0xBF80;
  dst[idx] = v;
}

// ---------------------------------------------------------------------------
// GEMM1: A = x fp32 [M,784] (converted to bf16 during staging),
//        B = W1b bf16 [1024,800] (signs, zero-padded), C = h1 bf16 [M,1024]
//        epilogue: relu(acc + b1[n]); K loop padded to 800 (zeros past 784)
// ---------------------------------------------------------------------------
__global__ __launch_bounds__(256, 2)
void gemm1_kernel(const float* __restrict__ X, const short* __restrict__ Wb,
                  const float* __restrict__ bias, short* __restrict__ H) {
  constexpr int K = 784, KP = 800, NP = 1024, NR = 1000;
  __shared__ short As[128 * 32];
  __shared__ short Bs[128 * 32];

  const int tid = threadIdx.x;
  const int lane = tid & 63;
  const int wave = tid >> 6;
  const int wm = wave >> 1, wn = wave & 1;
  const int l15 = lane & 15;
  const int quad = lane >> 4;
  const int m0 = blockIdx.y * 128;
  const int n0 = blockIdx.x * 128;

  // A staging (manual fp32->bf16): thread covers row=tid>>1, 16 k at aks
  const int ar = tid >> 1;
  const int aks = (tid & 1) * 16;
  const float* xrow = X + (size_t)(m0 + ar) * K;
  short* adst = As + ar * 32 + aks;

  // B staging via global_load_lds: wave covers 16 rows/pass, 2 passes
  const int br = wave * 16 + (lane >> 2);
  const int bks = (lane & 3) * 8;
  const short* brow0 = Wb + (size_t)(n0 + br) * KP + bks;
  short* bdst = Bs + (wave * 16) * 32;  // wave-uniform

  f32x4 acc[4][4];
#pragma unroll
  for (int i = 0; i < 4; ++i)
#pragma unroll
    for (int j = 0; j < 4; ++j) acc[i][j] = (f32x4){0.f, 0.f, 0.f, 0.f};

  for (int k0 = 0; k0 < KP; k0 += 32) {
    // stage B (async)
    glds16(brow0 + k0, bdst);
    glds16(brow0 + k0 + (size_t)64 * KP, bdst + 64 * 32);
    // stage A with convert
    short tmp[16];
#pragma unroll
    for (int c = 0; c < 4; ++c) {
      const int kk = k0 + aks + c * 4;
      float4 f;
      if (kk < K)
        f = *(const float4*)(xrow + kk);
      else
        f = make_float4(0.f, 0.f, 0.f, 0.f);
      tmp[c * 4 + 0] = (short)f2bf(f.x);
      tmp[c * 4 + 1] = (short)f2bf(f.y);
      tmp[c * 4 + 2] = (short)f2bf(f.z);
      tmp[c * 4 + 3] = (short)f2bf(f.w);
    }
    *(bf16x8*)(adst) = *(bf16x8*)(tmp);
    *(bf16x8*)(adst + 8) = *(bf16x8*)(tmp + 8);

    __syncthreads();

    const short* abase = As + (size_t)(wm * 64 + l15) * 32 + quad * 8;
    const short* bbase = Bs + (size_t)(wn * 64 + l15) * 32 + quad * 8;
    bf16x8 af[4], bfr[4];
#pragma unroll
    for (int i = 0; i < 4; ++i) af[i] = *(const bf16x8*)(abase + i * 16 * 32);
#pragma unroll
    for (int j = 0; j < 4; ++j) bfr[j] = *(const bf16x8*)(bbase + j * 16 * 32);
#pragma unroll
    for (int i = 0; i < 4; ++i)
#pragma unroll
      for (int j = 0; j < 4; ++j)
        acc[i][j] = __builtin_amdgcn_mfma_f32_16x16x32_bf16(af[i], bfr[j], acc[i][j], 0, 0, 0);
    __syncthreads();
  }

#pragma unroll
  for (int j = 0; j < 4; ++j) {
    const int n = n0 + wn * 64 + j * 16 + l15;
    const float bv = (n < NR) ? bias[n] : 0.f;
#pragma unroll
    for (int i = 0; i < 4; ++i) {
      const int mr = m0 + wm * 64 + i * 16 + quad * 4;
#pragma unroll
      for (int r = 0; r < 4; ++r) {
        float v = acc[i][j][r] + bv;
        v = v > 0.f ? v : 0.f;
        H[(size_t)(mr + r) * NP + n] = (short)f2bf(v);
      }
    }
  }
}

// ---------------------------------------------------------------------------
// GEMM2: A = h1 bf16 [M,1024], B = W2b bf16 [512,1024], C = h2 bf16 [M,512]
//        epilogue: relu(acc + b2[n])
// ---------------------------------------------------------------------------
__global__ __launch_bounds__(256, 2)
void gemm2_kernel(const short* __restrict__ Hin, const short* __restrict__ Wb,
                  const float* __restrict__ bias, short* __restrict__ Hout) {
  constexpr int KP = 1024, NP = 512, NR = 500;
  __shared__ short As[128 * 32];
  __shared__ short Bs[128 * 32];

  const int tid = threadIdx.x;
  const int lane = tid & 63;
  const int wave = tid >> 6;
  const int wm = wave >> 1, wn = wave & 1;
  const int l15 = lane & 15;
  const int quad = lane >> 4;
  const int m0 = blockIdx.y * 128;
  const int n0 = blockIdx.x * 128;

  const int sr = wave * 16 + (lane >> 2);
  const int sks = (lane & 3) * 8;
  const short* arow0 = Hin + (size_t)(m0 + sr) * KP + sks;
  const short* brow0 = Wb + (size_t)(n0 + sr) * KP + sks;
  short* adst = As + (wave * 16) * 32;
  short* bdst = Bs + (wave * 16) * 32;

  f32x4 acc[4][4];
#pragma unroll
  for (int i = 0; i < 4; ++i)
#pragma unroll
    for (int j = 0; j < 4; ++j) acc[i][j] = (f32x4){0.f, 0.f, 0.f, 0.f};

  for (int k0 = 0; k0 < KP; k0 += 32) {
    glds16(arow0 + k0, adst);
    glds16(arow0 + k0 + (size_t)64 * KP, adst + 64 * 32);
    glds16(brow0 + k0, bdst);
    glds16(brow0 + k0 + (size_t)64 * KP, bdst + 64 * 32);
    __syncthreads();

    const short* abase = As + (size_t)(wm * 64 + l15) * 32 + quad * 8;
    const short* bbase = Bs + (size_t)(wn * 64 + l15) * 32 + quad * 8;
    bf16x8 af[4], bfr[4];
#pragma unroll
    for (int i = 0; i < 4; ++i) af[i] = *(const bf16x8*)(abase + i * 16 * 32);
#pragma unroll
    for (int j = 0; j < 4; ++j) bfr[j] = *(const bf16x8*)(bbase + j * 16 * 32);
#pragma unroll
    for (int i = 0; i < 4; ++i)
#pragma unroll
      for (int j = 0; j < 4; ++j)
        acc[i][j] = __builtin_amdgcn_mfma_f32_16x16x32_bf16(af[i], bfr[j], acc[i][j], 0, 0, 0);
    __syncthreads();
  }

#pragma unroll
  for (int j = 0; j < 4; ++j) {
    const int n = n0 + wn * 64 + j * 16 + l15;
    const float bv = (n < NR) ? bias[n] : 0.f;
#pragma unroll
    for (int i = 0; i < 4; ++i) {
      const int mr = m0 + wm * 64 + i * 16 + quad * 4;
#pragma unroll
      for (int r = 0; r < 4; ++r) {
        float v = acc[i][j][r] + bv;
        v = v > 0.f ? v : 0.f;
        Hout[(size_t)(mr + r) * NP + n] = (short)f2bf(v);
      }
    }
  }
}

// ---------------------------------------------------------------------------
// GEMM3: A = h2 bf16 [M,512], B = W3b bf16 [16,512] (resident in LDS),
//        C = out fp32 [M,10]; BM=128, BN=16; wave w handles rows [w*32,w*32+32)
// ---------------------------------------------------------------------------
__global__ __launch_bounds__(256, 2)
void gemm3_kernel(const short* __restrict__ Hin, const short* __restrict__ Wb,
                  const float* __restrict__ bias, float* __restrict__ Out) {
  constexpr int KP = 512;
  constexpr int BSTRIDE = 520;  // pad 512+8: avoids 16-way bank conflict
  __shared__ short As[128 * 32];
  __shared__ short Bs[16 * BSTRIDE];

  const int tid = threadIdx.x;
  const int lane = tid & 63;
  const int wave = tid >> 6;
  const int l15 = lane & 15;
  const int quad = lane >> 4;
  const int m0 = blockIdx.x * 128;

  // preload all of W3b (16x512) into LDS once
  for (int t = tid; t < 16 * 512 / 8; t += 256) {
    int n = (t * 8) / 512;
    int k = (t * 8) % 512;
    *(bf16x8*)(Bs + n * BSTRIDE + k) = *(const bf16x8*)(Wb + t * 8);
  }

  const int sr = wave * 16 + (lane >> 2);
  const int sks = (lane & 3) * 8;
  const short* arow0 = Hin + (size_t)(m0 + sr) * KP + sks;
  short* adst = As + (wave * 16) * 32;

  f32x4 acc[2];
#pragma unroll
  for (int i = 0; i < 2; ++i) acc[i] = (f32x4){0.f, 0.f, 0.f, 0.f};

  for (int k0 = 0; k0 < KP; k0 += 32) {
    glds16(arow0 + k0, adst);
    glds16(arow0 + k0 + (size_t)64 * KP, adst + 64 * 32);
    __syncthreads();

    bf16x8 bfr = *(const bf16x8*)(Bs + l15 * BSTRIDE + k0 + quad * 8);
#pragma unroll
    for (int i = 0; i < 2; ++i) {
      bf16x8 af = *(const bf16x8*)(As + (size_t)(wave * 32 + i * 16 + l15) * 32 + quad * 8);
      acc[i] = __builtin_amdgcn_mfma_f32_16x16x32_bf16(af, bfr, acc[i], 0, 0, 0);
    }
    __syncthreads();
  }

  if (l15 < 10) {
    const float bv = bias[l15];
#pragma unroll
    for (int i = 0; i < 2; ++i)
#pragma unroll
      for (int r = 0; r < 4; ++r) {
        const int mr = m0 + wave * 32 + i * 16 + quad * 4 + r;
        Out[(size_t)mr * 10 + l15] = acc[i][r] + bv;
      }
  }
}

// ---------------------------------------------------------------------------
extern "C" void kernel_launch(void* const* d_in, const int* in_sizes, int n_in,
                              void* d_out, int out_size, void* d_ws, size_t ws_size,
                              hipStream_t stream) {
  const float* x = (const float*)d_in[0];
  const float* W1 = (const float*)d_in[1];
  const float* b1 = (const float*)d_in[2];
  const float* W2 = (const float*)d_in[3];
  const float* b2 = (const float*)d_in[4];
  const float* W3 = (const float*)d_in[5];
  const float* b3 = (const float*)d_in[6];
  float* out = (float*)d_out;

  // workspace layout (total ~204 MB)
  uint8_t* p = (uint8_t*)d_ws;
  short* W1b = (short*)p; p += (size_t)1024 * 800 * 2;
  short* W2b = (short*)p; p += (size_t)512 * 1024 * 2;
  short* W3b = (short*)p; p += (size_t)16 * 512 * 2;
  short* h1 = (short*)p; p += (size_t)65536 * 1024 * 2;
  short* h2 = (short*)p; p += (size_t)65536 * 512 * 2;

  binarize_kernel<<<(1024 * 800 + 255) / 256, 256, 0, stream>>>(W1, 1000, 784, W1b, 1024, 800);
  binarize_kernel<<<(512 * 1024 + 255) / 256, 256, 0, stream>>>(W2, 500, 1000, W2b, 512, 1024);
  binarize_kernel<<<(16 * 512 + 255) / 256, 256, 0, stream>>>(W3, 10, 500, W3b, 16, 512);

  gemm1_kernel<<<dim3(8, 512), 256, 0, stream>>>(x, W1b, b1, h1);
  gemm2_kernel<<<dim3(4, 512), 256, 0, stream>>>(h1, W2b, b2, h2);
  gemm3_kernel<<<512, 256, 0, stream>>>(h2, W3b, b3, out);
}

// Round 2
// 672.268 us; speedup vs baseline: 1.0599x; 1.0599x over previous
//
#include <hip/hip_runtime.h>
#include <stdint.h>

// ---------------------------------------------------------------------------
// Binary (sign) weight 3-layer MLP, round 2:
//   gemm1: h1 = relu(x[65536,784]f32 @ sign(W1)^T + b1) -> bf16 [65536,1024]
//   gemm2: h2 = relu(h1 @ sign(W2)^T + b2)              -> bf16 [65536,512]
//   gemm3: out = h2 @ sign(W3)^T + b3                   -> f32  [65536,10]
// R2 changes: BN=512 blocks (8 waves) to kill A re-reads; 32x32x16 MFMA to
// double FLOP per LDS byte. gemm2 reads h1 exactly once.
// ---------------------------------------------------------------------------

typedef __attribute__((ext_vector_type(8))) short bf16x8;
typedef __attribute__((ext_vector_type(4))) float f32x4;
typedef __attribute__((ext_vector_type(16))) float f32x16;

typedef const __attribute__((address_space(1))) unsigned int* as1_u32p;
typedef __attribute__((address_space(3))) unsigned int* as3_u32p;

__device__ __forceinline__ void glds16(const void* g, void* l) {
  // async global->LDS, 16B/lane; LDS dest = wave-uniform base + lane*16
  __builtin_amdgcn_global_load_lds((as1_u32p)g, (as3_u32p)l, 16, 0, 0);
}

__device__ __forceinline__ unsigned short f2bf(float f) {
  union { float f; unsigned u; } c;
  c.f = f;
  unsigned u = c.u;
  u += 0x7FFFu + ((u >> 16) & 1u);  // RTNE
  return (unsigned short)(u >> 16);
}

// ---------------------------------------------------------------------------
// Binarize + zero-pad: dst[n,k] = (n<Ns && k<Ks) ? sign(src[n,k]) : 0 (bf16)
// ---------------------------------------------------------------------------
__global__ void binarize_kernel(const float* __restrict__ src, int Ns, int Ks,
                                short* __restrict__ dst, int Np, int Kp) {
  int idx = blockIdx.x * 256 + threadIdx.x;
  if (idx >= Np * Kp) return;
  int n = idx / Kp;
  int k = idx - n * Kp;
  short v = 0;
  if (n < Ns && k < Ks)
    v = (src[n * Ks + k] >= 0.0f) ? (short)0x3F80 : (short)0xBF80;
  dst[idx] = v;
}

// ---------------------------------------------------------------------------
// GEMM1: X f32 [M,784] (bf16-converted in staging) x W1b [1024,800] -> h1
// BM=128, BN=512 (grid 2 x 512), 512 threads = 8 waves (2m x 4n),
// wave tile 64x128 as 2x4 frags of 32x32, BK=32 (two x16 k-steps).
// ---------------------------------------------------------------------------
__global__ __launch_bounds__(512, 1)
void gemm1_kernel(const float* __restrict__ X, const short* __restrict__ Wb,
                  const float* __restrict__ bias, short* __restrict__ H) {
  constexpr int K = 784, KP = 800, NP = 1024, NR = 1000;
  __shared__ short As[128 * 32];
  __shared__ short Bs[512 * 32];

  const int tid = threadIdx.x;
  const int lane = tid & 63;
  const int wave = tid >> 6;          // 0..7
  const int wm = wave >> 2;           // 0..1
  const int wn = wave & 3;            // 0..3
  const int l31 = lane & 31;
  const int kh = lane >> 5;           // 0..1
  const int m0 = blockIdx.y * 128;
  const int n0 = blockIdx.x * 512;

  // A staging (fp32->bf16): thread t covers row=t>>2, 8 k at (t&3)*8
  const int ar = tid >> 2;
  const int aks = (tid & 3) * 8;
  const float* xrow = X + (size_t)(m0 + ar) * K + aks;
  short* adst = As + ar * 32 + aks;

  // B staging via glds16: wave covers 64 rows (4 passes of 16)
  const int brow = wave * 64 + (lane >> 2);
  const int bks = (lane & 3) * 8;
  const short* bsrc = Wb + (size_t)(n0 + brow) * KP + bks;
  short* bdst = Bs + (wave * 64) * 32;  // wave-uniform

  f32x16 acc[2][4];
#pragma unroll
  for (int i = 0; i < 2; ++i)
#pragma unroll
    for (int j = 0; j < 4; ++j)
#pragma unroll
      for (int r = 0; r < 16; ++r) acc[i][j][r] = 0.f;

  for (int k0 = 0; k0 < KP; k0 += 32) {
    // stage B (async, 4 x 16 rows per wave)
#pragma unroll
    for (int p = 0; p < 4; ++p)
      glds16(bsrc + k0 + (size_t)(p * 16) * KP, bdst + (p * 16) * 32);

    // stage A with convert (guard only matters on last iter)
    short tmp[8];
#pragma unroll
    for (int c = 0; c < 2; ++c) {
      const int kk = k0 + aks + c * 4;
      float4 f;
      if (kk < K)
        f = *(const float4*)(xrow + k0 + c * 4);
      else
        f = make_float4(0.f, 0.f, 0.f, 0.f);
      tmp[c * 4 + 0] = (short)f2bf(f.x);
      tmp[c * 4 + 1] = (short)f2bf(f.y);
      tmp[c * 4 + 2] = (short)f2bf(f.z);
      tmp[c * 4 + 3] = (short)f2bf(f.w);
    }
    *(bf16x8*)(adst) = *(bf16x8*)(tmp);

    __syncthreads();

#pragma unroll
    for (int ks = 0; ks < 2; ++ks) {
      const int koff = ks * 16 + kh * 8;
      bf16x8 af[2], bfr[4];
#pragma unroll
      for (int i = 0; i < 2; ++i)
        af[i] = *(const bf16x8*)(As + (size_t)(wm * 64 + i * 32 + l31) * 32 + koff);
#pragma unroll
      for (int j = 0; j < 4; ++j)
        bfr[j] = *(const bf16x8*)(Bs + (size_t)(wn * 128 + j * 32 + l31) * 32 + koff);
#pragma unroll
      for (int i = 0; i < 2; ++i)
#pragma unroll
        for (int j = 0; j < 4; ++j)
          acc[i][j] = __builtin_amdgcn_mfma_f32_32x32x16_bf16(af[i], bfr[j], acc[i][j], 0, 0, 0);
    }
    __syncthreads();
  }

  // epilogue: C layout col=lane&31, row=(reg&3)+8*(reg>>2)+4*(lane>>5)
#pragma unroll
  for (int j = 0; j < 4; ++j) {
    const int n = n0 + wn * 128 + j * 32 + l31;
    const float bv = (n < NR) ? bias[n] : 0.f;
#pragma unroll
    for (int i = 0; i < 2; ++i) {
#pragma unroll
      for (int r = 0; r < 16; ++r) {
        const int row = (r & 3) + 8 * (r >> 2) + 4 * kh;
        const int m = m0 + wm * 64 + i * 32 + row;
        float v = acc[i][j][r] + bv;
        v = v > 0.f ? v : 0.f;
        H[(size_t)m * NP + n] = (short)f2bf(v);
      }
    }
  }
}

// ---------------------------------------------------------------------------
// GEMM2: h1 bf16 [M,1024] x W2b [512,1024] -> h2 bf16 [M,512]
// BM=128, BN=512 = full N (grid 512 m-blocks): h1 read exactly once.
// ---------------------------------------------------------------------------
__global__ __launch_bounds__(512, 1)
void gemm2_kernel(const short* __restrict__ Hin, const short* __restrict__ Wb,
                  const float* __restrict__ bias, short* __restrict__ Hout) {
  constexpr int KP = 1024, NP = 512, NR = 500;
  __shared__ short As[128 * 32];
  __shared__ short Bs[512 * 32];

  const int tid = threadIdx.x;
  const int lane = tid & 63;
  const int wave = tid >> 6;
  const int wm = wave >> 2;
  const int wn = wave & 3;
  const int l31 = lane & 31;
  const int kh = lane >> 5;
  const int m0 = blockIdx.x * 128;

  // A staging: each wave 16 rows (1 glds16)
  const int arow = wave * 16 + (lane >> 2);
  const int sks = (lane & 3) * 8;
  const short* asrc = Hin + (size_t)(m0 + arow) * KP + sks;
  short* adst = As + (wave * 16) * 32;

  // B staging: each wave 64 rows (4 glds16)
  const int brow = wave * 64 + (lane >> 2);
  const short* bsrc = Wb + (size_t)brow * KP + sks;
  short* bdst = Bs + (wave * 64) * 32;

  f32x16 acc[2][4];
#pragma unroll
  for (int i = 0; i < 2; ++i)
#pragma unroll
    for (int j = 0; j < 4; ++j)
#pragma unroll
      for (int r = 0; r < 16; ++r) acc[i][j][r] = 0.f;

  for (int k0 = 0; k0 < KP; k0 += 32) {
    glds16(asrc + k0, adst);
#pragma unroll
    for (int p = 0; p < 4; ++p)
      glds16(bsrc + k0 + (size_t)(p * 16) * KP, bdst + (p * 16) * 32);
    __syncthreads();

#pragma unroll
    for (int ks = 0; ks < 2; ++ks) {
      const int koff = ks * 16 + kh * 8;
      bf16x8 af[2], bfr[4];
#pragma unroll
      for (int i = 0; i < 2; ++i)
        af[i] = *(const bf16x8*)(As + (size_t)(wm * 64 + i * 32 + l31) * 32 + koff);
#pragma unroll
      for (int j = 0; j < 4; ++j)
        bfr[j] = *(const bf16x8*)(Bs + (size_t)(wn * 128 + j * 32 + l31) * 32 + koff);
#pragma unroll
      for (int i = 0; i < 2; ++i)
#pragma unroll
        for (int j = 0; j < 4; ++j)
          acc[i][j] = __builtin_amdgcn_mfma_f32_32x32x16_bf16(af[i], bfr[j], acc[i][j], 0, 0, 0);
    }
    __syncthreads();
  }

#pragma unroll
  for (int j = 0; j < 4; ++j) {
    const int n = wn * 128 + j * 32 + l31;
    const float bv = (n < NR) ? bias[n] : 0.f;
#pragma unroll
    for (int i = 0; i < 2; ++i) {
#pragma unroll
      for (int r = 0; r < 16; ++r) {
        const int row = (r & 3) + 8 * (r >> 2) + 4 * kh;
        const int m = m0 + wm * 64 + i * 32 + row;
        float v = acc[i][j][r] + bv;
        v = v > 0.f ? v : 0.f;
        Hout[(size_t)m * NP + n] = (short)f2bf(v);
      }
    }
  }
}

// ---------------------------------------------------------------------------
// GEMM3: h2 bf16 [M,512] x W3b [16,512] (LDS-resident) -> out f32 [M,10]
// BM=128, BN=16; 256 threads; 16x16x32 MFMA (unchanged from round 1).
// ---------------------------------------------------------------------------
__global__ __launch_bounds__(256, 2)
void gemm3_kernel(const short* __restrict__ Hin, const short* __restrict__ Wb,
                  const float* __restrict__ bias, float* __restrict__ Out) {
  constexpr int KP = 512;
  constexpr int BSTRIDE = 520;  // pad: avoids 16-way bank conflict
  __shared__ short As[128 * 32];
  __shared__ short Bs[16 * BSTRIDE];

  const int tid = threadIdx.x;
  const int lane = tid & 63;
  const int wave = tid >> 6;
  const int l15 = lane & 15;
  const int quad = lane >> 4;
  const int m0 = blockIdx.x * 128;

  for (int t = tid; t < 16 * 512 / 8; t += 256) {
    int n = (t * 8) / 512;
    int k = (t * 8) % 512;
    *(bf16x8*)(Bs + n * BSTRIDE + k) = *(const bf16x8*)(Wb + t * 8);
  }

  const int sr = wave * 16 + (lane >> 2);
  const int sks = (lane & 3) * 8;
  const short* arow0 = Hin + (size_t)(m0 + sr) * KP + sks;
  short* adst = As + (wave * 16) * 32;

  f32x4 acc[2];
#pragma unroll
  for (int i = 0; i < 2; ++i) acc[i] = (f32x4){0.f, 0.f, 0.f, 0.f};

  for (int k0 = 0; k0 < KP; k0 += 32) {
    glds16(arow0 + k0, adst);
    glds16(arow0 + k0 + (size_t)64 * KP, adst + 64 * 32);
    __syncthreads();

    bf16x8 bfr = *(const bf16x8*)(Bs + l15 * BSTRIDE + k0 + quad * 8);
#pragma unroll
    for (int i = 0; i < 2; ++i) {
      bf16x8 af = *(const bf16x8*)(As + (size_t)(wave * 32 + i * 16 + l15) * 32 + quad * 8);
      acc[i] = __builtin_amdgcn_mfma_f32_16x16x32_bf16(af, bfr, acc[i], 0, 0, 0);
    }
    __syncthreads();
  }

  if (l15 < 10) {
    const float bv = bias[l15];
#pragma unroll
    for (int i = 0; i < 2; ++i)
#pragma unroll
      for (int r = 0; r < 4; ++r) {
        const int mr = m0 + wave * 32 + i * 16 + quad * 4 + r;
        Out[(size_t)mr * 10 + l15] = acc[i][r] + bv;
      }
  }
}

// ---------------------------------------------------------------------------
extern "C" void kernel_launch(void* const* d_in, const int* in_sizes, int n_in,
                              void* d_out, int out_size, void* d_ws, size_t ws_size,
                              hipStream_t stream) {
  const float* x = (const float*)d_in[0];
  const float* W1 = (const float*)d_in[1];
  const float* b1 = (const float*)d_in[2];
  const float* W2 = (const float*)d_in[3];
  const float* b2 = (const float*)d_in[4];
  const float* W3 = (const float*)d_in[5];
  const float* b3 = (const float*)d_in[6];
  float* out = (float*)d_out;

  uint8_t* p = (uint8_t*)d_ws;
  short* W1b = (short*)p; p += (size_t)1024 * 800 * 2;
  short* W2b = (short*)p; p += (size_t)512 * 1024 * 2;
  short* W3b = (short*)p; p += (size_t)16 * 512 * 2;
  short* h1 = (short*)p; p += (size_t)65536 * 1024 * 2;
  short* h2 = (short*)p; p += (size_t)65536 * 512 * 2;

  binarize_kernel<<<(1024 * 800 + 255) / 256, 256, 0, stream>>>(W1, 1000, 784, W1b, 1024, 800);
  binarize_kernel<<<(512 * 1024 + 255) / 256, 256, 0, stream>>>(W2, 500, 1000, W2b, 512, 1024);
  binarize_kernel<<<(16 * 512 + 255) / 256, 256, 0, stream>>>(W3, 10, 500, W3b, 16, 512);

  gemm1_kernel<<<dim3(2, 512), 512, 0, stream>>>(x, W1b, b1, h1);
  gemm2_kernel<<<512, 512, 0, stream>>>(h1, W2b, b2, h2);
  gemm3_kernel<<<512, 256, 0, stream>>>(h2, W3b, b3, out);
}

// Round 3
// 612.885 us; speedup vs baseline: 1.1626x; 1.0969x over previous
//
#include <hip/hip_runtime.h>
#include <stdint.h>

// ---------------------------------------------------------------------------
// Binary (sign) weight 3-layer MLP, round 3:
//   convert_x: x f32 [65536,784] -> Xp bf16 [65536,800] (zero-padded K)
//   gemm1: h1 = relu(Xp @ sign(W1)^T + b1) -> bf16 [65536,1024]
//   gemm2: h2 = relu(h1 @ sign(W2)^T + b2) -> bf16 [65536,512]
//   gemm3: out = h2 @ sign(W3)^T + b3      -> f32  [65536,10]
// R3: back to the proven m97 tile (128x128, 256thr, 4x4 frags 16x16x32,
// 64 AGPR acc -> ~4 blocks/CU). R2's 64x128 wave tile (128 AGPR) collapsed
// occupancy to 1 block/CU (23%, MfmaUtil 13.5%). gemm1's fp32-X traffic fixed
// by one-time bf16 pre-convert; 8x N-tile re-reads of 105 MB Xp live in L3.
// Xp aliases h2's workspace region (lifetimes disjoint); host-side ws_size
// branch falls back to R1's fused-convert gemm1 if scratch < 242 MB.
// ---------------------------------------------------------------------------

typedef __attribute__((ext_vector_type(8))) short bf16x8;
typedef __attribute__((ext_vector_type(4))) float f32x4;

typedef const __attribute__((address_space(1))) unsigned int* as1_u32p;
typedef __attribute__((address_space(3))) unsigned int* as3_u32p;

__device__ __forceinline__ void glds16(const void* g, void* l) {
  // async global->LDS, 16B/lane; LDS dest = wave-uniform base + lane*16
  __builtin_amdgcn_global_load_lds((as1_u32p)g, (as3_u32p)l, 16, 0, 0);
}

__device__ __forceinline__ unsigned short f2bf(float f) {
  union { float f; unsigned u; } c;
  c.f = f;
  unsigned u = c.u;
  u += 0x7FFFu + ((u >> 16) & 1u);  // RTNE
  return (unsigned short)(u >> 16);
}

// ---------------------------------------------------------------------------
// Binarize + zero-pad: dst[n,k] = (n<Ns && k<Ks) ? sign(src[n,k]) : 0 (bf16)
// ---------------------------------------------------------------------------
__global__ void binarize_kernel(const float* __restrict__ src, int Ns, int Ks,
                                short* __restrict__ dst, int Np, int Kp) {
  int idx = blockIdx.x * 256 + threadIdx.x;
  if (idx >= Np * Kp) return;
  int n = idx / Kp;
  int k = idx - n * Kp;
  short v = 0;
  if (n < Ns && k < Ks)
    v = (src[n * Ks + k] >= 0.0f) ? (short)0x3F80 : (short)0xBF80;
  dst[idx] = v;
}

// ---------------------------------------------------------------------------
// convert_x: X f32 [65536,784] -> Xp bf16 [65536,800], cols 784..800 zeroed.
// One thread = 8 contiguous cols (784 = 98*8, so groups 0..97 full, 98..99 pad)
// ---------------------------------------------------------------------------
__global__ void convert_x_kernel(const float* __restrict__ X, short* __restrict__ Xp) {
  const int g = blockIdx.x * 256 + threadIdx.x;  // 65536*100 groups
  if (g >= 65536 * 100) return;
  const int row = g / 100;
  const int c = (g - row * 100) * 8;
  short tmp[8];
  if (c < 784) {
    const float* s = X + (size_t)row * 784 + c;
    float4 f0 = *(const float4*)s;
    float4 f1 = *(const float4*)(s + 4);
    tmp[0] = (short)f2bf(f0.x); tmp[1] = (short)f2bf(f0.y);
    tmp[2] = (short)f2bf(f0.z); tmp[3] = (short)f2bf(f0.w);
    tmp[4] = (short)f2bf(f1.x); tmp[5] = (short)f2bf(f1.y);
    tmp[6] = (short)f2bf(f1.z); tmp[7] = (short)f2bf(f1.w);
  } else {
#pragma unroll
    for (int i = 0; i < 8; ++i) tmp[i] = 0;
  }
  *(bf16x8*)(Xp + (size_t)row * 800 + c) = *(bf16x8*)(tmp);
}

// ---------------------------------------------------------------------------
// m97-structure GEMM: A bf16 [M,KP] x Wb bf16 [NP,KP] -> relu(.+bias) bf16 [M,NP]
// BM=BN=128, BK=32, 256 threads (4 waves, 2x2), 4x4 frags of 16x16x32.
// ---------------------------------------------------------------------------
template <int KP, int NP, int NR>
__global__ __launch_bounds__(256, 2)
void gemm_bb(const short* __restrict__ A, const short* __restrict__ Wb,
             const float* __restrict__ bias, short* __restrict__ Hout) {
  __shared__ short As[128 * 32];
  __shared__ short Bs[128 * 32];

  const int tid = threadIdx.x;
  const int lane = tid & 63;
  const int wave = tid >> 6;
  const int wm = wave >> 1, wn = wave & 1;
  const int l15 = lane & 15;
  const int quad = lane >> 4;
  const int m0 = blockIdx.y * 128;
  const int n0 = blockIdx.x * 128;

  const int sr = wave * 16 + (lane >> 2);
  const int sks = (lane & 3) * 8;
  const short* asrc = A + (size_t)(m0 + sr) * KP + sks;
  const short* bsrc = Wb + (size_t)(n0 + sr) * KP + sks;
  short* adst = As + (wave * 16) * 32;
  short* bdst = Bs + (wave * 16) * 32;

  f32x4 acc[4][4];
#pragma unroll
  for (int i = 0; i < 4; ++i)
#pragma unroll
    for (int j = 0; j < 4; ++j) acc[i][j] = (f32x4){0.f, 0.f, 0.f, 0.f};

  for (int k0 = 0; k0 < KP; k0 += 32) {
    glds16(asrc + k0, adst);
    glds16(asrc + k0 + (size_t)64 * KP, adst + 64 * 32);
    glds16(bsrc + k0, bdst);
    glds16(bsrc + k0 + (size_t)64 * KP, bdst + 64 * 32);
    __syncthreads();

    const short* abase = As + (size_t)(wm * 64 + l15) * 32 + quad * 8;
    const short* bbase = Bs + (size_t)(wn * 64 + l15) * 32 + quad * 8;
    bf16x8 af[4], bfr[4];
#pragma unroll
    for (int i = 0; i < 4; ++i) af[i] = *(const bf16x8*)(abase + i * 16 * 32);
#pragma unroll
    for (int j = 0; j < 4; ++j) bfr[j] = *(const bf16x8*)(bbase + j * 16 * 32);
#pragma unroll
    for (int i = 0; i < 4; ++i)
#pragma unroll
      for (int j = 0; j < 4; ++j)
        acc[i][j] = __builtin_amdgcn_mfma_f32_16x16x32_bf16(af[i], bfr[j], acc[i][j], 0, 0, 0);
    __syncthreads();
  }

#pragma unroll
  for (int j = 0; j < 4; ++j) {
    const int n = n0 + wn * 64 + j * 16 + l15;
    const float bv = (n < NR) ? bias[n] : 0.f;
#pragma unroll
    for (int i = 0; i < 4; ++i) {
      const int mr = m0 + wm * 64 + i * 16 + quad * 4;
#pragma unroll
      for (int r = 0; r < 4; ++r) {
        float v = acc[i][j][r] + bv;
        v = v > 0.f ? v : 0.f;
        Hout[(size_t)(mr + r) * NP + n] = (short)f2bf(v);
      }
    }
  }
}

// ---------------------------------------------------------------------------
// Fallback GEMM1 (small-ws path): fused fp32->bf16 convert in A staging (R1).
// ---------------------------------------------------------------------------
__global__ __launch_bounds__(256, 2)
void gemm1_fused_kernel(const float* __restrict__ X, const short* __restrict__ Wb,
                        const float* __restrict__ bias, short* __restrict__ H) {
  constexpr int K = 784, KP = 800, NP = 1024, NR = 1000;
  __shared__ short As[128 * 32];
  __shared__ short Bs[128 * 32];

  const int tid = threadIdx.x;
  const int lane = tid & 63;
  const int wave = tid >> 6;
  const int wm = wave >> 1, wn = wave & 1;
  const int l15 = lane & 15;
  const int quad = lane >> 4;
  const int m0 = blockIdx.y * 128;
  const int n0 = blockIdx.x * 128;

  const int ar = tid >> 1;
  const int aks = (tid & 1) * 16;
  const float* xrow = X + (size_t)(m0 + ar) * K;
  short* adst = As + ar * 32 + aks;

  const int br = wave * 16 + (lane >> 2);
  const int bks = (lane & 3) * 8;
  const short* brow0 = Wb + (size_t)(n0 + br) * KP + bks;
  short* bdst = Bs + (wave * 16) * 32;

  f32x4 acc[4][4];
#pragma unroll
  for (int i = 0; i < 4; ++i)
#pragma unroll
    for (int j = 0; j < 4; ++j) acc[i][j] = (f32x4){0.f, 0.f, 0.f, 0.f};

  for (int k0 = 0; k0 < KP; k0 += 32) {
    glds16(brow0 + k0, bdst);
    glds16(brow0 + k0 + (size_t)64 * KP, bdst + 64 * 32);
    short tmp[16];
#pragma unroll
    for (int c = 0; c < 4; ++c) {
      const int kk = k0 + aks + c * 4;
      float4 f;
      if (kk < K)
        f = *(const float4*)(xrow + kk);
      else
        f = make_float4(0.f, 0.f, 0.f, 0.f);
      tmp[c * 4 + 0] = (short)f2bf(f.x);
      tmp[c * 4 + 1] = (short)f2bf(f.y);
      tmp[c * 4 + 2] = (short)f2bf(f.z);
      tmp[c * 4 + 3] = (short)f2bf(f.w);
    }
    *(bf16x8*)(adst) = *(bf16x8*)(tmp);
    *(bf16x8*)(adst + 8) = *(bf16x8*)(tmp + 8);

    __syncthreads();

    const short* abase = As + (size_t)(wm * 64 + l15) * 32 + quad * 8;
    const short* bbase = Bs + (size_t)(wn * 64 + l15) * 32 + quad * 8;
    bf16x8 af[4], bfr[4];
#pragma unroll
    for (int i = 0; i < 4; ++i) af[i] = *(const bf16x8*)(abase + i * 16 * 32);
#pragma unroll
    for (int j = 0; j < 4; ++j) bfr[j] = *(const bf16x8*)(bbase + j * 16 * 32);
#pragma unroll
    for (int i = 0; i < 4; ++i)
#pragma unroll
      for (int j = 0; j < 4; ++j)
        acc[i][j] = __builtin_amdgcn_mfma_f32_16x16x32_bf16(af[i], bfr[j], acc[i][j], 0, 0, 0);
    __syncthreads();
  }

#pragma unroll
  for (int j = 0; j < 4; ++j) {
    const int n = n0 + wn * 64 + j * 16 + l15;
    const float bv = (n < NR) ? bias[n] : 0.f;
#pragma unroll
    for (int i = 0; i < 4; ++i) {
      const int mr = m0 + wm * 64 + i * 16 + quad * 4;
#pragma unroll
      for (int r = 0; r < 4; ++r) {
        float v = acc[i][j][r] + bv;
        v = v > 0.f ? v : 0.f;
        H[(size_t)(mr + r) * NP + n] = (short)f2bf(v);
      }
    }
  }
}

// ---------------------------------------------------------------------------
// GEMM3: h2 bf16 [M,512] x W3b [16,512] (LDS-resident) -> out f32 [M,10]
// ---------------------------------------------------------------------------
__global__ __launch_bounds__(256, 2)
void gemm3_kernel(const short* __restrict__ Hin, const short* __restrict__ Wb,
                  const float* __restrict__ bias, float* __restrict__ Out) {
  constexpr int KP = 512;
  constexpr int BSTRIDE = 520;  // pad: avoids 16-way bank conflict
  __shared__ short As[128 * 32];
  __shared__ short Bs[16 * BSTRIDE];

  const int tid = threadIdx.x;
  const int lane = tid & 63;
  const int wave = tid >> 6;
  const int l15 = lane & 15;
  const int quad = lane >> 4;
  const int m0 = blockIdx.x * 128;

  for (int t = tid; t < 16 * 512 / 8; t += 256) {
    int n = (t * 8) / 512;
    int k = (t * 8) % 512;
    *(bf16x8*)(Bs + n * BSTRIDE + k) = *(const bf16x8*)(Wb + t * 8);
  }

  const int sr = wave * 16 + (lane >> 2);
  const int sks = (lane & 3) * 8;
  const short* arow0 = Hin + (size_t)(m0 + sr) * KP + sks;
  short* adst = As + (wave * 16) * 32;

  f32x4 acc[2];
#pragma unroll
  for (int i = 0; i < 2; ++i) acc[i] = (f32x4){0.f, 0.f, 0.f, 0.f};

  for (int k0 = 0; k0 < KP; k0 += 32) {
    glds16(arow0 + k0, adst);
    glds16(arow0 + k0 + (size_t)64 * KP, adst + 64 * 32);
    __syncthreads();

    bf16x8 bfr = *(const bf16x8*)(Bs + l15 * BSTRIDE + k0 + quad * 8);
#pragma unroll
    for (int i = 0; i < 2; ++i) {
      bf16x8 af = *(const bf16x8*)(As + (size_t)(wave * 32 + i * 16 + l15) * 32 + quad * 8);
      acc[i] = __builtin_amdgcn_mfma_f32_16x16x32_bf16(af, bfr, acc[i], 0, 0, 0);
    }
    __syncthreads();
  }

  if (l15 < 10) {
    const float bv = bias[l15];
#pragma unroll
    for (int i = 0; i < 2; ++i)
#pragma unroll
      for (int r = 0; r < 4; ++r) {
        const int mr = m0 + wave * 32 + i * 16 + quad * 4 + r;
        Out[(size_t)mr * 10 + l15] = acc[i][r] + bv;
      }
  }
}

// ---------------------------------------------------------------------------
extern "C" void kernel_launch(void* const* d_in, const int* in_sizes, int n_in,
                              void* d_out, int out_size, void* d_ws, size_t ws_size,
                              hipStream_t stream) {
  const float* x = (const float*)d_in[0];
  const float* W1 = (const float*)d_in[1];
  const float* b1 = (const float*)d_in[2];
  const float* W2 = (const float*)d_in[3];
  const float* b2 = (const float*)d_in[4];
  const float* W3 = (const float*)d_in[5];
  const float* b3 = (const float*)d_in[6];
  float* out = (float*)d_out;

  const size_t szW1 = (size_t)1024 * 800 * 2;
  const size_t szW2 = (size_t)512 * 1024 * 2;
  const size_t szW3 = (size_t)16 * 512 * 2;
  const size_t szH1 = (size_t)65536 * 1024 * 2;
  const size_t szXp = (size_t)65536 * 800 * 2;   // 104.9 MB
  const size_t need = szW1 + szW2 + szW3 + szH1 + szXp;  // ~241.8 MB

  uint8_t* p = (uint8_t*)d_ws;
  short* W1b = (short*)p; p += szW1;
  short* W2b = (short*)p; p += szW2;
  short* W3b = (short*)p; p += szW3;
  short* h1 = (short*)p; p += szH1;
  short* Z = (short*)p;  // Xp (convert+gemm1) then h2 (gemm2+gemm3) — disjoint lifetimes

  binarize_kernel<<<(1024 * 800 + 255) / 256, 256, 0, stream>>>(W1, 1000, 784, W1b, 1024, 800);
  binarize_kernel<<<(512 * 1024 + 255) / 256, 256, 0, stream>>>(W2, 500, 1000, W2b, 512, 1024);
  binarize_kernel<<<(16 * 512 + 255) / 256, 256, 0, stream>>>(W3, 10, 500, W3b, 16, 512);

  if (ws_size >= need) {
    short* Xp = Z;
    short* h2 = Z;
    convert_x_kernel<<<(65536 * 100 + 255) / 256, 256, 0, stream>>>(x, Xp);
    gemm_bb<800, 1024, 1000><<<dim3(8, 512), 256, 0, stream>>>(Xp, W1b, b1, h1);
    gemm_bb<1024, 512, 500><<<dim3(4, 512), 256, 0, stream>>>(h1, W2b, b2, h2);
    gemm3_kernel<<<512, 256, 0, stream>>>(h2, W3b, b3, out);
  } else {
    short* h2 = Z;  // only 67 MB needed past h1 in this path
    gemm1_fused_kernel<<<dim3(8, 512), 256, 0, stream>>>(x, W1b, b1, h1);
    gemm_bb<1024, 512, 500><<<dim3(4, 512), 256, 0, stream>>>(h1, W2b, b2, h2);
    gemm3_kernel<<<512, 256, 0, stream>>>(h2, W3b, b3, out);
  }
}

// Round 4
// 608.360 us; speedup vs baseline: 1.1712x; 1.0074x over previous
//
#include <hip/hip_runtime.h>
#include <stdint.h>

// ---------------------------------------------------------------------------
// Binary (sign) weight 3-layer MLP, round 4:
//   gemm1: h1 = relu(x[65536,784]f32 @ sign(W1)^T + b1) -> bf16 [65536,1024]
//          (fp32->bf16 convert fused into A staging)
//   gemm2: h2 = relu(h1 @ sign(W2)^T + b2)              -> bf16 [65536,512]
//   gemm3: out = h2 @ sign(W3)^T + b3                   -> f32  [65536,10]
// R4: XCD-aware block swizzle — the G N-tiles of one M-tile get dispatch ids
// with equal (d%8) residue and consecutive time-slots, so they co-reside on
// one XCD and share its L2 for the A panel (R3 showed 4.2x A over-fetch from
// cross-XCD scatter: FETCH 445 MB vs 105 ideal). convert_x dropped — with
// L2-shared A-reads, fused fp32 staging is cheaper than a separate pass.
// Tile: proven m97 structure (128x128, 256 thr, 4x4 frags 16x16x32 bf16).
// ---------------------------------------------------------------------------

typedef __attribute__((ext_vector_type(8))) short bf16x8;
typedef __attribute__((ext_vector_type(4))) float f32x4;

typedef const __attribute__((address_space(1))) unsigned int* as1_u32p;
typedef __attribute__((address_space(3))) unsigned int* as3_u32p;

__device__ __forceinline__ void glds16(const void* g, void* l) {
  // async global->LDS, 16B/lane; LDS dest = wave-uniform base + lane*16
  __builtin_amdgcn_global_load_lds((as1_u32p)g, (as3_u32p)l, 16, 0, 0);
}

__device__ __forceinline__ unsigned short f2bf(float f) {
  union { float f; unsigned u; } c;
  c.f = f;
  unsigned u = c.u;
  u += 0x7FFFu + ((u >> 16) & 1u);  // RTNE
  return (unsigned short)(u >> 16);
}

// ---------------------------------------------------------------------------
// Binarize + zero-pad: dst[n,k] = (n<Ns && k<Ks) ? sign(src[n,k]) : 0 (bf16)
// ---------------------------------------------------------------------------
__global__ void binarize_kernel(const float* __restrict__ src, int Ns, int Ks,
                                short* __restrict__ dst, int Np, int Kp) {
  int idx = blockIdx.x * 256 + threadIdx.x;
  if (idx >= Np * Kp) return;
  int n = idx / Kp;
  int k = idx - n * Kp;
  short v = 0;
  if (n < Ns && k < Ks)
    v = (src[n * Ks + k] >= 0.0f) ? (short)0x3F80 : (short)0xBF80;
  dst[idx] = v;
}

// ---------------------------------------------------------------------------
// GEMM1 (fused convert): X f32 [65536,784] x W1b bf16 [1024,800] -> h1 bf16
// 1-D grid of 4096 = 512 M-tiles x 8 N-tiles, XCD swizzle G=8.
// ---------------------------------------------------------------------------
__global__ __launch_bounds__(256, 2)
void gemm1_kernel(const float* __restrict__ X, const short* __restrict__ Wb,
                  const float* __restrict__ bias, short* __restrict__ H) {
  constexpr int K = 784, KP = 800, NP = 1024, NR = 1000;
  __shared__ short As[128 * 32];
  __shared__ short Bs[128 * 32];

  // XCD-aware swizzle: d%8 ~ XCD; same-M N-tiles share residue + adjacent slot
  const int d = blockIdx.x;
  const int xcd = d & 7;
  const int j = d >> 3;              // time-slot within XCD, [0,512)
  const int m0 = ((xcd << 6) + (j >> 3)) * 128;  // 64 M-tiles per XCD
  const int n0 = (j & 7) * 128;

  const int tid = threadIdx.x;
  const int lane = tid & 63;
  const int wave = tid >> 6;
  const int wm = wave >> 1, wn = wave & 1;
  const int l15 = lane & 15;
  const int quad = lane >> 4;

  // A staging (fp32->bf16): thread covers row=tid>>1, 16 k at (tid&1)*16
  const int ar = tid >> 1;
  const int aks = (tid & 1) * 16;
  const float* xrow = X + (size_t)(m0 + ar) * K;
  short* adst = As + ar * 32 + aks;

  // B staging via glds16: wave covers 16 rows/pass, 2 passes
  const int br = wave * 16 + (lane >> 2);
  const int bks = (lane & 3) * 8;
  const short* brow0 = Wb + (size_t)(n0 + br) * KP + bks;
  short* bdst = Bs + (wave * 16) * 32;  // wave-uniform

  f32x4 acc[4][4];
#pragma unroll
  for (int i = 0; i < 4; ++i)
#pragma unroll
    for (int j2 = 0; j2 < 4; ++j2) acc[i][j2] = (f32x4){0.f, 0.f, 0.f, 0.f};

  for (int k0 = 0; k0 < KP; k0 += 32) {
    glds16(brow0 + k0, bdst);
    glds16(brow0 + k0 + (size_t)64 * KP, bdst + 64 * 32);
    short tmp[16];
#pragma unroll
    for (int c = 0; c < 4; ++c) {
      const int kk = k0 + aks + c * 4;
      float4 f;
      if (kk < K)
        f = *(const float4*)(xrow + kk);
      else
        f = make_float4(0.f, 0.f, 0.f, 0.f);
      tmp[c * 4 + 0] = (short)f2bf(f.x);
      tmp[c * 4 + 1] = (short)f2bf(f.y);
      tmp[c * 4 + 2] = (short)f2bf(f.z);
      tmp[c * 4 + 3] = (short)f2bf(f.w);
    }
    *(bf16x8*)(adst) = *(bf16x8*)(tmp);
    *(bf16x8*)(adst + 8) = *(bf16x8*)(tmp + 8);

    __syncthreads();

    const short* abase = As + (size_t)(wm * 64 + l15) * 32 + quad * 8;
    const short* bbase = Bs + (size_t)(wn * 64 + l15) * 32 + quad * 8;
    bf16x8 af[4], bfr[4];
#pragma unroll
    for (int i = 0; i < 4; ++i) af[i] = *(const bf16x8*)(abase + i * 16 * 32);
#pragma unroll
    for (int j2 = 0; j2 < 4; ++j2) bfr[j2] = *(const bf16x8*)(bbase + j2 * 16 * 32);
#pragma unroll
    for (int i = 0; i < 4; ++i)
#pragma unroll
      for (int j2 = 0; j2 < 4; ++j2)
        acc[i][j2] = __builtin_amdgcn_mfma_f32_16x16x32_bf16(af[i], bfr[j2], acc[i][j2], 0, 0, 0);
    __syncthreads();
  }

#pragma unroll
  for (int j2 = 0; j2 < 4; ++j2) {
    const int n = n0 + wn * 64 + j2 * 16 + l15;
    const float bv = (n < NR) ? bias[n] : 0.f;
#pragma unroll
    for (int i = 0; i < 4; ++i) {
      const int mr = m0 + wm * 64 + i * 16 + quad * 4;
#pragma unroll
      for (int r = 0; r < 4; ++r) {
        float v = acc[i][j2][r] + bv;
        v = v > 0.f ? v : 0.f;
        H[(size_t)(mr + r) * NP + n] = (short)f2bf(v);
      }
    }
  }
}

// ---------------------------------------------------------------------------
// m97-structure GEMM, bf16 A: used for gemm2. XCD swizzle, GRP N-tiles.
// ---------------------------------------------------------------------------
template <int KP, int NP, int NR, int GRP, int GRPLOG>
__global__ __launch_bounds__(256, 2)
void gemm_bb(const short* __restrict__ A, const short* __restrict__ Wb,
             const float* __restrict__ bias, short* __restrict__ Hout) {
  __shared__ short As[128 * 32];
  __shared__ short Bs[128 * 32];

  const int d = blockIdx.x;
  const int xcd = d & 7;
  const int j = d >> 3;
  const int m0 = ((xcd << 6) + (j >> GRPLOG)) * 128;
  const int n0 = (j & (GRP - 1)) * 128;

  const int tid = threadIdx.x;
  const int lane = tid & 63;
  const int wave = tid >> 6;
  const int wm = wave >> 1, wn = wave & 1;
  const int l15 = lane & 15;
  const int quad = lane >> 4;

  const int sr = wave * 16 + (lane >> 2);
  const int sks = (lane & 3) * 8;
  const short* asrc = A + (size_t)(m0 + sr) * KP + sks;
  const short* bsrc = Wb + (size_t)(n0 + sr) * KP + sks;
  short* adst = As + (wave * 16) * 32;
  short* bdst = Bs + (wave * 16) * 32;

  f32x4 acc[4][4];
#pragma unroll
  for (int i = 0; i < 4; ++i)
#pragma unroll
    for (int j2 = 0; j2 < 4; ++j2) acc[i][j2] = (f32x4){0.f, 0.f, 0.f, 0.f};

  for (int k0 = 0; k0 < KP; k0 += 32) {
    glds16(asrc + k0, adst);
    glds16(asrc + k0 + (size_t)64 * KP, adst + 64 * 32);
    glds16(bsrc + k0, bdst);
    glds16(bsrc + k0 + (size_t)64 * KP, bdst + 64 * 32);
    __syncthreads();

    const short* abase = As + (size_t)(wm * 64 + l15) * 32 + quad * 8;
    const short* bbase = Bs + (size_t)(wn * 64 + l15) * 32 + quad * 8;
    bf16x8 af[4], bfr[4];
#pragma unroll
    for (int i = 0; i < 4; ++i) af[i] = *(const bf16x8*)(abase + i * 16 * 32);
#pragma unroll
    for (int j2 = 0; j2 < 4; ++j2) bfr[j2] = *(const bf16x8*)(bbase + j2 * 16 * 32);
#pragma unroll
    for (int i = 0; i < 4; ++i)
#pragma unroll
      for (int j2 = 0; j2 < 4; ++j2)
        acc[i][j2] = __builtin_amdgcn_mfma_f32_16x16x32_bf16(af[i], bfr[j2], acc[i][j2], 0, 0, 0);
    __syncthreads();
  }

#pragma unroll
  for (int j2 = 0; j2 < 4; ++j2) {
    const int n = n0 + wn * 64 + j2 * 16 + l15;
    const float bv = (n < NR) ? bias[n] : 0.f;
#pragma unroll
    for (int i = 0; i < 4; ++i) {
      const int mr = m0 + wm * 64 + i * 16 + quad * 4;
#pragma unroll
      for (int r = 0; r < 4; ++r) {
        float v = acc[i][j2][r] + bv;
        v = v > 0.f ? v : 0.f;
        Hout[(size_t)(mr + r) * NP + n] = (short)f2bf(v);
      }
    }
  }
}

// ---------------------------------------------------------------------------
// GEMM3: h2 bf16 [M,512] x W3b [16,512] (LDS-resident) -> out f32 [M,10]
// ---------------------------------------------------------------------------
__global__ __launch_bounds__(256, 2)
void gemm3_kernel(const short* __restrict__ Hin, const short* __restrict__ Wb,
                  const float* __restrict__ bias, float* __restrict__ Out) {
  constexpr int KP = 512;
  constexpr int BSTRIDE = 520;  // pad: avoids 16-way bank conflict
  __shared__ short As[128 * 32];
  __shared__ short Bs[16 * BSTRIDE];

  const int tid = threadIdx.x;
  const int lane = tid & 63;
  const int wave = tid >> 6;
  const int l15 = lane & 15;
  const int quad = lane >> 4;
  const int m0 = blockIdx.x * 128;

  for (int t = tid; t < 16 * 512 / 8; t += 256) {
    int n = (t * 8) / 512;
    int k = (t * 8) % 512;
    *(bf16x8*)(Bs + n * BSTRIDE + k) = *(const bf16x8*)(Wb + t * 8);
  }

  const int sr = wave * 16 + (lane >> 2);
  const int sks = (lane & 3) * 8;
  const short* arow0 = Hin + (size_t)(m0 + sr) * KP + sks;
  short* adst = As + (wave * 16) * 32;

  f32x4 acc[2];
#pragma unroll
  for (int i = 0; i < 2; ++i) acc[i] = (f32x4){0.f, 0.f, 0.f, 0.f};

  for (int k0 = 0; k0 < KP; k0 += 32) {
    glds16(arow0 + k0, adst);
    glds16(arow0 + k0 + (size_t)64 * KP, adst + 64 * 32);
    __syncthreads();

    bf16x8 bfr = *(const bf16x8*)(Bs + l15 * BSTRIDE + k0 + quad * 8);
#pragma unroll
    for (int i = 0; i < 2; ++i) {
      bf16x8 af = *(const bf16x8*)(As + (size_t)(wave * 32 + i * 16 + l15) * 32 + quad * 8);
      acc[i] = __builtin_amdgcn_mfma_f32_16x16x32_bf16(af, bfr, acc[i], 0, 0, 0);
    }
    __syncthreads();
  }

  if (l15 < 10) {
    const float bv = bias[l15];
#pragma unroll
    for (int i = 0; i < 2; ++i)
#pragma unroll
      for (int r = 0; r < 4; ++r) {
        const int mr = m0 + wave * 32 + i * 16 + quad * 4 + r;
        Out[(size_t)mr * 10 + l15] = acc[i][r] + bv;
      }
  }
}

// ---------------------------------------------------------------------------
extern "C" void kernel_launch(void* const* d_in, const int* in_sizes, int n_in,
                              void* d_out, int out_size, void* d_ws, size_t ws_size,
                              hipStream_t stream) {
  const float* x = (const float*)d_in[0];
  const float* W1 = (const float*)d_in[1];
  const float* b1 = (const float*)d_in[2];
  const float* W2 = (const float*)d_in[3];
  const float* b2 = (const float*)d_in[4];
  const float* W3 = (const float*)d_in[5];
  const float* b3 = (const float*)d_in[6];
  float* out = (float*)d_out;

  uint8_t* p = (uint8_t*)d_ws;
  short* W1b = (short*)p; p += (size_t)1024 * 800 * 2;
  short* W2b = (short*)p; p += (size_t)512 * 1024 * 2;
  short* W3b = (short*)p; p += (size_t)16 * 512 * 2;
  short* h1 = (short*)p; p += (size_t)65536 * 1024 * 2;
  short* h2 = (short*)p;  // 67 MB; total ~204 MB

  binarize_kernel<<<(1024 * 800 + 255) / 256, 256, 0, stream>>>(W1, 1000, 784, W1b, 1024, 800);
  binarize_kernel<<<(512 * 1024 + 255) / 256, 256, 0, stream>>>(W2, 500, 1000, W2b, 512, 1024);
  binarize_kernel<<<(16 * 512 + 255) / 256, 256, 0, stream>>>(W3, 10, 500, W3b, 16, 512);

  gemm1_kernel<<<4096, 256, 0, stream>>>(x, W1b, b1, h1);
  gemm_bb<1024, 512, 500, 4, 2><<<2048, 256, 0, stream>>>(h1, W2b, b2, h2);
  gemm3_kernel<<<512, 256, 0, stream>>>(h2, W3b, b3, out);
}

// Round 5
// 599.827 us; speedup vs baseline: 1.1879x; 1.0142x over previous
//
#include <hip/hip_runtime.h>
#include <stdint.h>

// ---------------------------------------------------------------------------
// Binary (sign) weight 3-layer MLP, round 5:
//   gemm1: h1 = relu(x[65536,784]f32 @ sign(W1)^T + b1) -> bf16 [65536,1024]
//          fused fp32->bf16 convert, LDS double-buffer, 1 barrier/iter,
//          X register-prefetched one iteration ahead (R4 was latency-
//          serialized on the sync X-load -> convert -> ds_write chain).
//   gemm2: h2 = relu(h1 @ sign(W2)^T + b2)              -> bf16 [65536,512]
//          unchanged swizzled m97 (so its counters surface for attribution).
//   gemm3: out = h2 @ sign(W3)^T + b3                   -> f32  [65536,10]
//          rewritten: BM=64, full-K LDS staging (64 KB), W3 frags in VGPRs,
//          single barrier, 16 back-to-back MFMAs -> pure DMA-bound.
// XCD swizzle (d%8) kept everywhere it matters: R4 proved it cuts A over-
// fetch 445->142 MB.
// ---------------------------------------------------------------------------

typedef __attribute__((ext_vector_type(8))) short bf16x8;
typedef __attribute__((ext_vector_type(4))) float f32x4;

typedef const __attribute__((address_space(1))) unsigned int* as1_u32p;
typedef __attribute__((address_space(3))) unsigned int* as3_u32p;

__device__ __forceinline__ void glds16(const void* g, void* l) {
  // async global->LDS, 16B/lane; LDS dest = wave-uniform base + lane*16
  __builtin_amdgcn_global_load_lds((as1_u32p)g, (as3_u32p)l, 16, 0, 0);
}

__device__ __forceinline__ unsigned short f2bf(float f) {
  union { float f; unsigned u; } c;
  c.f = f;
  unsigned u = c.u;
  u += 0x7FFFu + ((u >> 16) & 1u);  // RTNE
  return (unsigned short)(u >> 16);
}

// ---------------------------------------------------------------------------
// Binarize + zero-pad: dst[n,k] = (n<Ns && k<Ks) ? sign(src[n,k]) : 0 (bf16)
// ---------------------------------------------------------------------------
__global__ void binarize_kernel(const float* __restrict__ src, int Ns, int Ks,
                                short* __restrict__ dst, int Np, int Kp) {
  int idx = blockIdx.x * 256 + threadIdx.x;
  if (idx >= Np * Kp) return;
  int n = idx / Kp;
  int k = idx - n * Kp;
  short v = 0;
  if (n < Ns && k < Ks)
    v = (src[n * Ks + k] >= 0.0f) ? (short)0x3F80 : (short)0xBF80;
  dst[idx] = v;
}

// ---------------------------------------------------------------------------
// GEMM1: X f32 [65536,784] x W1b bf16 [1024,800] -> h1 bf16 [65536,1024]
// 128x128 tile, dbuf LDS, 1 barrier/iter, X prefetch. Grid 4096, swizzle G=8.
// ---------------------------------------------------------------------------
__global__ __launch_bounds__(256, 2)
void gemm1_kernel(const float* __restrict__ X, const short* __restrict__ Wb,
                  const float* __restrict__ bias, short* __restrict__ H) {
  constexpr int K = 784, KP = 800, NP = 1024, NR = 1000;
  __shared__ short As[2][128 * 32];
  __shared__ short Bs[2][128 * 32];

  const int d = blockIdx.x;
  const int xcd = d & 7;
  const int jj = d >> 3;
  const int m0 = ((xcd << 6) + (jj >> 3)) * 128;
  const int n0 = (jj & 7) * 128;

  const int tid = threadIdx.x;
  const int lane = tid & 63;
  const int wave = tid >> 6;
  const int wm = wave >> 1, wn = wave & 1;
  const int l15 = lane & 15;
  const int quad = lane >> 4;

  // A staging: thread covers row=tid>>1, 16 k-elems at (tid&1)*16
  const int ar = tid >> 1;
  const int aks = (tid & 1) * 16;
  const float* xrow = X + (size_t)(m0 + ar) * K;

  // B staging via glds16: wave covers 16 rows/call, 2 calls
  const int br = wave * 16 + (lane >> 2);
  const int bks = (lane & 3) * 8;
  const short* brow0 = Wb + (size_t)(n0 + br) * KP + bks;

  float4 xf[4];
  auto loadX = [&](int k0) {
#pragma unroll
    for (int c = 0; c < 4; ++c) {
      const int kk = k0 + aks + c * 4;
      if (kk < K)
        xf[c] = *(const float4*)(xrow + kk);
      else
        xf[c] = make_float4(0.f, 0.f, 0.f, 0.f);
    }
  };
  auto stage = [&](int k0) {
    const int buf = (k0 >> 5) & 1;
    short* bd = &Bs[buf][(wave * 16) * 32];
    glds16(brow0 + k0, bd);
    glds16(brow0 + k0 + (size_t)64 * KP, bd + 64 * 32);
    short tmp[16];
#pragma unroll
    for (int c = 0; c < 4; ++c) {
      tmp[c * 4 + 0] = (short)f2bf(xf[c].x);
      tmp[c * 4 + 1] = (short)f2bf(xf[c].y);
      tmp[c * 4 + 2] = (short)f2bf(xf[c].z);
      tmp[c * 4 + 3] = (short)f2bf(xf[c].w);
    }
    short* ad = &As[buf][ar * 32 + aks];
    *(bf16x8*)(ad) = *(bf16x8*)(tmp);
    *(bf16x8*)(ad + 8) = *(bf16x8*)(tmp + 8);
  };

  f32x4 acc[4][4];
#pragma unroll
  for (int i = 0; i < 4; ++i)
#pragma unroll
    for (int j2 = 0; j2 < 4; ++j2) acc[i][j2] = (f32x4){0.f, 0.f, 0.f, 0.f};

  // prologue: stage iter 0 (one-time sync X wait), prefetch X for iter 1
  loadX(0);
  stage(0);
  loadX(32);

  for (int k0 = 0; k0 < KP; k0 += 32) {
    __syncthreads();  // staging(k0) drained; xf(k0+32) also arrived
    if (k0 + 32 < KP) {
      stage(k0 + 32);                   // writes buf^, converts arrived regs
      if (k0 + 64 < KP) loadX(k0 + 64); // in flight across compute(k0)
    }
    const int buf = (k0 >> 5) & 1;
    const short* abase = &As[buf][(wm * 64 + l15) * 32 + quad * 8];
    const short* bbase = &Bs[buf][(wn * 64 + l15) * 32 + quad * 8];
    bf16x8 af[4], bfr[4];
#pragma unroll
    for (int i = 0; i < 4; ++i) af[i] = *(const bf16x8*)(abase + i * 16 * 32);
#pragma unroll
    for (int j2 = 0; j2 < 4; ++j2) bfr[j2] = *(const bf16x8*)(bbase + j2 * 16 * 32);
#pragma unroll
    for (int i = 0; i < 4; ++i)
#pragma unroll
      for (int j2 = 0; j2 < 4; ++j2)
        acc[i][j2] = __builtin_amdgcn_mfma_f32_16x16x32_bf16(af[i], bfr[j2], acc[i][j2], 0, 0, 0);
  }

#pragma unroll
  for (int j2 = 0; j2 < 4; ++j2) {
    const int n = n0 + wn * 64 + j2 * 16 + l15;
    const float bv = (n < NR) ? bias[n] : 0.f;
#pragma unroll
    for (int i = 0; i < 4; ++i) {
      const int mr = m0 + wm * 64 + i * 16 + quad * 4;
#pragma unroll
      for (int r = 0; r < 4; ++r) {
        float v = acc[i][j2][r] + bv;
        v = v > 0.f ? v : 0.f;
        H[(size_t)(mr + r) * NP + n] = (short)f2bf(v);
      }
    }
  }
}

// ---------------------------------------------------------------------------
// GEMM2: m97-structure, swizzled (unchanged from R4). h1 x W2b -> h2.
// ---------------------------------------------------------------------------
template <int KP, int NP, int NR, int GRP, int GRPLOG>
__global__ __launch_bounds__(256, 2)
void gemm_bb(const short* __restrict__ A, const short* __restrict__ Wb,
             const float* __restrict__ bias, short* __restrict__ Hout) {
  __shared__ short As[128 * 32];
  __shared__ short Bs[128 * 32];

  const int d = blockIdx.x;
  const int xcd = d & 7;
  const int j = d >> 3;
  const int m0 = ((xcd << 6) + (j >> GRPLOG)) * 128;
  const int n0 = (j & (GRP - 1)) * 128;

  const int tid = threadIdx.x;
  const int lane = tid & 63;
  const int wave = tid >> 6;
  const int wm = wave >> 1, wn = wave & 1;
  const int l15 = lane & 15;
  const int quad = lane >> 4;

  const int sr = wave * 16 + (lane >> 2);
  const int sks = (lane & 3) * 8;
  const short* asrc = A + (size_t)(m0 + sr) * KP + sks;
  const short* bsrc = Wb + (size_t)(n0 + sr) * KP + sks;
  short* adst = As + (wave * 16) * 32;
  short* bdst = Bs + (wave * 16) * 32;

  f32x4 acc[4][4];
#pragma unroll
  for (int i = 0; i < 4; ++i)
#pragma unroll
    for (int j2 = 0; j2 < 4; ++j2) acc[i][j2] = (f32x4){0.f, 0.f, 0.f, 0.f};

  for (int k0 = 0; k0 < KP; k0 += 32) {
    glds16(asrc + k0, adst);
    glds16(asrc + k0 + (size_t)64 * KP, adst + 64 * 32);
    glds16(bsrc + k0, bdst);
    glds16(bsrc + k0 + (size_t)64 * KP, bdst + 64 * 32);
    __syncthreads();

    const short* abase = As + (size_t)(wm * 64 + l15) * 32 + quad * 8;
    const short* bbase = Bs + (size_t)(wn * 64 + l15) * 32 + quad * 8;
    bf16x8 af[4], bfr[4];
#pragma unroll
    for (int i = 0; i < 4; ++i) af[i] = *(const bf16x8*)(abase + i * 16 * 32);
#pragma unroll
    for (int j2 = 0; j2 < 4; ++j2) bfr[j2] = *(const bf16x8*)(bbase + j2 * 16 * 32);
#pragma unroll
    for (int i = 0; i < 4; ++i)
#pragma unroll
      for (int j2 = 0; j2 < 4; ++j2)
        acc[i][j2] = __builtin_amdgcn_mfma_f32_16x16x32_bf16(af[i], bfr[j2], acc[i][j2], 0, 0, 0);
    __syncthreads();
  }

#pragma unroll
  for (int j2 = 0; j2 < 4; ++j2) {
    const int n = n0 + wn * 64 + j2 * 16 + l15;
    const float bv = (n < NR) ? bias[n] : 0.f;
#pragma unroll
    for (int i = 0; i < 4; ++i) {
      const int mr = m0 + wm * 64 + i * 16 + quad * 4;
#pragma unroll
      for (int r = 0; r < 4; ++r) {
        float v = acc[i][j2][r] + bv;
        v = v > 0.f ? v : 0.f;
        Hout[(size_t)(mr + r) * NP + n] = (short)f2bf(v);
      }
    }
  }
}

// ---------------------------------------------------------------------------
// GEMM3: h2 bf16 [65536,512] x W3b [16,512] -> out f32 [65536,10]
// BM=64, full K staged to 64 KB LDS (single barrier), W3 frags in VGPRs.
// 16-way LDS bank conflicts on A-frag reads accepted: staging DMA dominates.
// ---------------------------------------------------------------------------
__global__ __launch_bounds__(256, 2)
void gemm3_kernel(const short* __restrict__ Hin, const short* __restrict__ Wb,
                  const float* __restrict__ bias, float* __restrict__ Out) {
  constexpr int KP = 512;
  __shared__ short As[64 * KP];  // 64 KB -> 2 blocks/CU

  const int tid = threadIdx.x;
  const int lane = tid & 63;
  const int wave = tid >> 6;
  const int l15 = lane & 15;
  const int quad = lane >> 4;
  const int m0 = blockIdx.x * 64;

  // B fragments to registers: lane needs W3b[l15][kk*32+quad*8 .. +8)
  bf16x8 bw[16];
#pragma unroll
  for (int kk = 0; kk < 16; ++kk)
    bw[kk] = *(const bf16x8*)(Wb + l15 * KP + kk * 32 + quad * 8);

  // stage 64 rows: wave w stages rows [w*16, w*16+16), one row per glds16
  // (64 lanes x 16B = 1024 B = one 512-elem bf16 row)
  const short* asrc = Hin + (size_t)(m0 + wave * 16) * KP + lane * 8;
  short* adst = As + (size_t)(wave * 16) * KP;
#pragma unroll
  for (int t = 0; t < 16; ++t)
    glds16(asrc + (size_t)t * KP, adst + (size_t)t * KP);

  __syncthreads();

  f32x4 acc = (f32x4){0.f, 0.f, 0.f, 0.f};
  const short* abase = As + (size_t)(wave * 16 + l15) * KP + quad * 8;
#pragma unroll
  for (int kk = 0; kk < 16; ++kk) {
    bf16x8 af = *(const bf16x8*)(abase + kk * 32);
    acc = __builtin_amdgcn_mfma_f32_16x16x32_bf16(af, bw[kk], acc, 0, 0, 0);
  }

  if (l15 < 10) {
    const float bv = bias[l15];
#pragma unroll
    for (int r = 0; r < 4; ++r) {
      const int mr = m0 + wave * 16 + quad * 4 + r;
      Out[(size_t)mr * 10 + l15] = acc[r] + bv;
    }
  }
}

// ---------------------------------------------------------------------------
extern "C" void kernel_launch(void* const* d_in, const int* in_sizes, int n_in,
                              void* d_out, int out_size, void* d_ws, size_t ws_size,
                              hipStream_t stream) {
  const float* x = (const float*)d_in[0];
  const float* W1 = (const float*)d_in[1];
  const float* b1 = (const float*)d_in[2];
  const float* W2 = (const float*)d_in[3];
  const float* b2 = (const float*)d_in[4];
  const float* W3 = (const float*)d_in[5];
  const float* b3 = (const float*)d_in[6];
  float* out = (float*)d_out;

  uint8_t* p = (uint8_t*)d_ws;
  short* W1b = (short*)p; p += (size_t)1024 * 800 * 2;
  short* W2b = (short*)p; p += (size_t)512 * 1024 * 2;
  short* W3b = (short*)p; p += (size_t)16 * 512 * 2;
  short* h1 = (short*)p; p += (size_t)65536 * 1024 * 2;
  short* h2 = (short*)p;  // 67 MB; total ~204 MB

  binarize_kernel<<<(1024 * 800 + 255) / 256, 256, 0, stream>>>(W1, 1000, 784, W1b, 1024, 800);
  binarize_kernel<<<(512 * 1024 + 255) / 256, 256, 0, stream>>>(W2, 500, 1000, W2b, 512, 1024);
  binarize_kernel<<<(16 * 512 + 255) / 256, 256, 0, stream>>>(W3, 10, 500, W3b, 16, 512);

  gemm1_kernel<<<4096, 256, 0, stream>>>(x, W1b, b1, h1);
  gemm_bb<1024, 512, 500, 4, 2><<<2048, 256, 0, stream>>>(h1, W2b, b2, h2);
  gemm3_kernel<<<1024, 256, 0, stream>>>(h2, W3b, b3, out);
}

// Round 6
// 575.843 us; speedup vs baseline: 1.2374x; 1.0417x over previous
//
#include <hip/hip_runtime.h>
#include <stdint.h>

// ---------------------------------------------------------------------------
// Binary (sign) weight 3-layer MLP, round 6:
//   convert_x: x f32 [65536,784] -> Xp bf16 [65536,832] (zero-pad K to 13*64)
//   gemm1: h1 = relu(Xp @ sign(W1)^T + b1) -> bf16 [65536,1024]
//   gemm2: h2 = relu(h1 @ sign(W2)^T + b2) -> bf16 [65536,512]
//   gemm3: out = h2 @ sign(W3)^T + b3      -> f32  [65536,10]
// R6 core change: XCD-swizzle KEPT (R4 proved 3.4x traffic cut) but the G
// same-M blocks now start their K-loop at ROTATED phases (sum commutes), so
// they stream disjoint K-slices -> no lockstep same-line contention (R4/R5's
// MLP collapse to 1 TB/s). BK=64 as two BK-32 sub-tiles: half the barrier
// drains, 32 MFMA per drain. glds16-only staging (no reg round-trip in loop).
// ---------------------------------------------------------------------------

typedef __attribute__((ext_vector_type(8))) short bf16x8;
typedef __attribute__((ext_vector_type(4))) float f32x4;

typedef const __attribute__((address_space(1))) unsigned int* as1_u32p;
typedef __attribute__((address_space(3))) unsigned int* as3_u32p;

__device__ __forceinline__ void glds16(const void* g, void* l) {
  __builtin_amdgcn_global_load_lds((as1_u32p)g, (as3_u32p)l, 16, 0, 0);
}

__device__ __forceinline__ unsigned short f2bf(float f) {
  union { float f; unsigned u; } c;
  c.f = f;
  unsigned u = c.u;
  u += 0x7FFFu + ((u >> 16) & 1u);  // RTNE
  return (unsigned short)(u >> 16);
}

// ---------------------------------------------------------------------------
__global__ void binarize_kernel(const float* __restrict__ src, int Ns, int Ks,
                                short* __restrict__ dst, int Np, int Kp) {
  int idx = blockIdx.x * 256 + threadIdx.x;
  if (idx >= Np * Kp) return;
  int n = idx / Kp;
  int k = idx - n * Kp;
  short v = 0;
  if (n < Ns && k < Ks)
    v = (src[n * Ks + k] >= 0.0f) ? (short)0x3F80 : (short)0xBF80;
  dst[idx] = v;
}

// ---------------------------------------------------------------------------
// convert_x: X f32 [65536,784] -> Xp bf16 [65536,832], cols 784..832 zeroed.
// One thread = 8 contiguous cols (832/8 = 104 groups/row; 784 = 98*8)
// ---------------------------------------------------------------------------
__global__ void convert_x_kernel(const float* __restrict__ X, short* __restrict__ Xp) {
  const int g = blockIdx.x * 256 + threadIdx.x;
  if (g >= 65536 * 104) return;
  const int row = g / 104;
  const int c = (g - row * 104) * 8;
  short tmp[8];
  if (c < 784) {
    const float* s = X + (size_t)row * 784 + c;
    float4 f0 = *(const float4*)s;
    float4 f1 = *(const float4*)(s + 4);
    tmp[0] = (short)f2bf(f0.x); tmp[1] = (short)f2bf(f0.y);
    tmp[2] = (short)f2bf(f0.z); tmp[3] = (short)f2bf(f0.w);
    tmp[4] = (short)f2bf(f1.x); tmp[5] = (short)f2bf(f1.y);
    tmp[6] = (short)f2bf(f1.z); tmp[7] = (short)f2bf(f1.w);
  } else {
#pragma unroll
    for (int i = 0; i < 8; ++i) tmp[i] = 0;
  }
  *(bf16x8*)(Xp + (size_t)row * 832 + c) = *(bf16x8*)(tmp);
}

// ---------------------------------------------------------------------------
// BK=64 GEMM: A bf16 [M,KP] x Wb bf16 [NP,KP] -> relu(.+bias) bf16 [M,NP]
// 128x128 tile, 256 thr, 4x4 frags of 16x16x32, two BK-32 sub-tiles/barrier.
// XCD swizzle (d%8) + K-phase rotation by n-index. NIT = KP/64.
// ---------------------------------------------------------------------------
template <int KP, int NIT, int NP, int NR, int GLOG>
__global__ __launch_bounds__(256, 2)
void gemm_bk64(const short* __restrict__ A, const short* __restrict__ Wb,
               const float* __restrict__ bias, short* __restrict__ Hout) {
  __shared__ short As0[128 * 32];
  __shared__ short As1[128 * 32];
  __shared__ short Bs0[128 * 32];
  __shared__ short Bs1[128 * 32];

  const int d = blockIdx.x;
  const int xcd = d & 7;
  const int slot = d >> 3;
  const int j = slot & ((1 << GLOG) - 1);              // n-tile index
  const int m0 = ((xcd << 6) + (slot >> GLOG)) * 128;  // 64 m-tiles per XCD
  const int n0 = j * 128;
  const int start = (j * NIT) >> GLOG;                 // K-phase rotation

  const int tid = threadIdx.x;
  const int lane = tid & 63;
  const int wave = tid >> 6;
  const int wm = wave >> 1, wn = wave & 1;
  const int l15 = lane & 15;
  const int quad = lane >> 4;

  const int sr = wave * 16 + (lane >> 2);
  const int sks = (lane & 3) * 8;
  const short* asrc = A + (size_t)(m0 + sr) * KP + sks;
  const short* bsrc = Wb + (size_t)(n0 + sr) * KP + sks;
  const int sdst = (wave * 16) * 32;  // wave-uniform LDS offset

  f32x4 acc[4][4];
#pragma unroll
  for (int i = 0; i < 4; ++i)
#pragma unroll
    for (int j2 = 0; j2 < 4; ++j2) acc[i][j2] = (f32x4){0.f, 0.f, 0.f, 0.f};

  for (int it = 0; it < NIT; ++it) {
    int kit = start + it;
    if (kit >= NIT) kit -= NIT;
    const int k0 = kit * 64;

    glds16(asrc + k0, As0 + sdst);
    glds16(asrc + k0 + (size_t)64 * KP, As0 + sdst + 64 * 32);
    glds16(asrc + k0 + 32, As1 + sdst);
    glds16(asrc + k0 + 32 + (size_t)64 * KP, As1 + sdst + 64 * 32);
    glds16(bsrc + k0, Bs0 + sdst);
    glds16(bsrc + k0 + (size_t)64 * KP, Bs0 + sdst + 64 * 32);
    glds16(bsrc + k0 + 32, Bs1 + sdst);
    glds16(bsrc + k0 + 32 + (size_t)64 * KP, Bs1 + sdst + 64 * 32);
    __syncthreads();

#pragma unroll
    for (int h = 0; h < 2; ++h) {
      const short* As = h ? As1 : Bs0 - 128 * 32;  // avoided; see below
      // (use explicit pointers instead of the trick above)
      const short* ab = (h ? As1 : As0) + (wm * 64 + l15) * 32 + quad * 8;
      const short* bb = (h ? Bs1 : Bs0) + (wn * 64 + l15) * 32 + quad * 8;
      bf16x8 af[4], bfr[4];
#pragma unroll
      for (int i = 0; i < 4; ++i) af[i] = *(const bf16x8*)(ab + i * 16 * 32);
#pragma unroll
      for (int j2 = 0; j2 < 4; ++j2) bfr[j2] = *(const bf16x8*)(bb + j2 * 16 * 32);
#pragma unroll
      for (int i = 0; i < 4; ++i)
#pragma unroll
        for (int j2 = 0; j2 < 4; ++j2)
          acc[i][j2] = __builtin_amdgcn_mfma_f32_16x16x32_bf16(af[i], bfr[j2], acc[i][j2], 0, 0, 0);
    }
    __syncthreads();
  }

#pragma unroll
  for (int j2 = 0; j2 < 4; ++j2) {
    const int n = n0 + wn * 64 + j2 * 16 + l15;
    const float bv = (n < NR) ? bias[n] : 0.f;
#pragma unroll
    for (int i = 0; i < 4; ++i) {
      const int mr = m0 + wm * 64 + i * 16 + quad * 4;
#pragma unroll
      for (int r = 0; r < 4; ++r) {
        float v = acc[i][j2][r] + bv;
        v = v > 0.f ? v : 0.f;
        Hout[(size_t)(mr + r) * NP + n] = (short)f2bf(v);
      }
    }
  }
}

// ---------------------------------------------------------------------------
// Fallback GEMM1 (small-ws): fused fp32->bf16 convert, m97 BK=32, KP=832.
// ---------------------------------------------------------------------------
__global__ __launch_bounds__(256, 2)
void gemm1_fused_kernel(const float* __restrict__ X, const short* __restrict__ Wb,
                        const float* __restrict__ bias, short* __restrict__ H) {
  constexpr int K = 784, KP = 832, NP = 1024, NR = 1000;
  __shared__ short As[128 * 32];
  __shared__ short Bs[128 * 32];

  const int tid = threadIdx.x;
  const int lane = tid & 63;
  const int wave = tid >> 6;
  const int wm = wave >> 1, wn = wave & 1;
  const int l15 = lane & 15;
  const int quad = lane >> 4;
  const int m0 = blockIdx.y * 128;
  const int n0 = blockIdx.x * 128;

  const int ar = tid >> 1;
  const int aks = (tid & 1) * 16;
  const float* xrow = X + (size_t)(m0 + ar) * K;
  short* adst = As + ar * 32 + aks;

  const int br = wave * 16 + (lane >> 2);
  const int bks = (lane & 3) * 8;
  const short* brow0 = Wb + (size_t)(n0 + br) * KP + bks;
  short* bdst = Bs + (wave * 16) * 32;

  f32x4 acc[4][4];
#pragma unroll
  for (int i = 0; i < 4; ++i)
#pragma unroll
    for (int j2 = 0; j2 < 4; ++j2) acc[i][j2] = (f32x4){0.f, 0.f, 0.f, 0.f};

  for (int k0 = 0; k0 < KP; k0 += 32) {
    glds16(brow0 + k0, bdst);
    glds16(brow0 + k0 + (size_t)64 * KP, bdst + 64 * 32);
    short tmp[16];
#pragma unroll
    for (int c = 0; c < 4; ++c) {
      const int kk = k0 + aks + c * 4;
      float4 f;
      if (kk + 3 < K)
        f = *(const float4*)(xrow + kk);
      else
        f = make_float4(0.f, 0.f, 0.f, 0.f);
      tmp[c * 4 + 0] = (short)f2bf(f.x);
      tmp[c * 4 + 1] = (short)f2bf(f.y);
      tmp[c * 4 + 2] = (short)f2bf(f.z);
      tmp[c * 4 + 3] = (short)f2bf(f.w);
    }
    *(bf16x8*)(adst) = *(bf16x8*)(tmp);
    *(bf16x8*)(adst + 8) = *(bf16x8*)(tmp + 8);
    __syncthreads();

    const short* abase = As + (size_t)(wm * 64 + l15) * 32 + quad * 8;
    const short* bbase = Bs + (size_t)(wn * 64 + l15) * 32 + quad * 8;
    bf16x8 af[4], bfr[4];
#pragma unroll
    for (int i = 0; i < 4; ++i) af[i] = *(const bf16x8*)(abase + i * 16 * 32);
#pragma unroll
    for (int j2 = 0; j2 < 4; ++j2) bfr[j2] = *(const bf16x8*)(bbase + j2 * 16 * 32);
#pragma unroll
    for (int i = 0; i < 4; ++i)
#pragma unroll
      for (int j2 = 0; j2 < 4; ++j2)
        acc[i][j2] = __builtin_amdgcn_mfma_f32_16x16x32_bf16(af[i], bfr[j2], acc[i][j2], 0, 0, 0);
    __syncthreads();
  }

#pragma unroll
  for (int j2 = 0; j2 < 4; ++j2) {
    const int n = n0 + wn * 64 + j2 * 16 + l15;
    const float bv = (n < NR) ? bias[n] : 0.f;
#pragma unroll
    for (int i = 0; i < 4; ++i) {
      const int mr = m0 + wm * 64 + i * 16 + quad * 4;
#pragma unroll
      for (int r = 0; r < 4; ++r) {
        float v = acc[i][j2][r] + bv;
        v = v > 0.f ? v : 0.f;
        H[(size_t)(mr + r) * NP + n] = (short)f2bf(v);
      }
    }
  }
}

// ---------------------------------------------------------------------------
// GEMM3: h2 bf16 [65536,512] x W3b [16,512] -> out f32 [65536,10]
// BM=64, full-K LDS staging (64 KB), W3 frags in VGPRs, single barrier.
// ---------------------------------------------------------------------------
__global__ __launch_bounds__(256, 2)
void gemm3_kernel(const short* __restrict__ Hin, const short* __restrict__ Wb,
                  const float* __restrict__ bias, float* __restrict__ Out) {
  constexpr int KP = 512;
  __shared__ short As[64 * KP];

  const int tid = threadIdx.x;
  const int lane = tid & 63;
  const int wave = tid >> 6;
  const int l15 = lane & 15;
  const int quad = lane >> 4;
  const int m0 = blockIdx.x * 64;

  bf16x8 bw[16];
#pragma unroll
  for (int kk = 0; kk < 16; ++kk)
    bw[kk] = *(const bf16x8*)(Wb + l15 * KP + kk * 32 + quad * 8);

  const short* asrc = Hin + (size_t)(m0 + wave * 16) * KP + lane * 8;
  short* adst = As + (size_t)(wave * 16) * KP;
#pragma unroll
  for (int t = 0; t < 16; ++t)
    glds16(asrc + (size_t)t * KP, adst + (size_t)t * KP);

  __syncthreads();

  f32x4 acc = (f32x4){0.f, 0.f, 0.f, 0.f};
  const short* abase = As + (size_t)(wave * 16 + l15) * KP + quad * 8;
#pragma unroll
  for (int kk = 0; kk < 16; ++kk) {
    bf16x8 af = *(const bf16x8*)(abase + kk * 32);
    acc = __builtin_amdgcn_mfma_f32_16x16x32_bf16(af, bw[kk], acc, 0, 0, 0);
  }

  if (l15 < 10) {
    const float bv = bias[l15];
#pragma unroll
    for (int r = 0; r < 4; ++r) {
      const int mr = m0 + wave * 16 + quad * 4 + r;
      Out[(size_t)mr * 10 + l15] = acc[r] + bv;
    }
  }
}

// ---------------------------------------------------------------------------
extern "C" void kernel_launch(void* const* d_in, const int* in_sizes, int n_in,
                              void* d_out, int out_size, void* d_ws, size_t ws_size,
                              hipStream_t stream) {
  const float* x = (const float*)d_in[0];
  const float* W1 = (const float*)d_in[1];
  const float* b1 = (const float*)d_in[2];
  const float* W2 = (const float*)d_in[3];
  const float* b2 = (const float*)d_in[4];
  const float* W3 = (const float*)d_in[5];
  const float* b3 = (const float*)d_in[6];
  float* out = (float*)d_out;

  const size_t szW1 = (size_t)1024 * 832 * 2;
  const size_t szW2 = (size_t)512 * 1024 * 2;
  const size_t szW3 = (size_t)16 * 512 * 2;
  const size_t szH1 = (size_t)65536 * 1024 * 2;
  const size_t szXp = (size_t)65536 * 832 * 2;  // 109 MB (shares Z with h2)
  const size_t need = szW1 + szW2 + szW3 + szH1 + szXp;  // ~246 MB

  uint8_t* p = (uint8_t*)d_ws;
  short* W1b = (short*)p; p += szW1;
  short* W2b = (short*)p; p += szW2;
  short* W3b = (short*)p; p += szW3;
  short* h1 = (short*)p; p += szH1;
  short* Z = (short*)p;  // Xp (convert+gemm1), then h2 (gemm2+gemm3)

  binarize_kernel<<<(1024 * 832 + 255) / 256, 256, 0, stream>>>(W1, 1000, 784, W1b, 1024, 832);
  binarize_kernel<<<(512 * 1024 + 255) / 256, 256, 0, stream>>>(W2, 500, 1000, W2b, 512, 1024);
  binarize_kernel<<<(16 * 512 + 255) / 256, 256, 0, stream>>>(W3, 10, 500, W3b, 16, 512);

  if (ws_size >= need) {
    short* Xp = Z;
    short* h2 = Z;
    convert_x_kernel<<<(65536 * 104 + 255) / 256, 256, 0, stream>>>(x, Xp);
    gemm_bk64<832, 13, 1024, 1000, 3><<<4096, 256, 0, stream>>>(Xp, W1b, b1, h1);
    gemm_bk64<1024, 16, 512, 500, 2><<<2048, 256, 0, stream>>>(h1, W2b, b2, h2);
    gemm3_kernel<<<1024, 256, 0, stream>>>(h2, W3b, b3, out);
  } else {
    short* h2 = Z;
    gemm1_fused_kernel<<<dim3(8, 512), 256, 0, stream>>>(x, W1b, b1, h1);
    gemm_bk64<1024, 16, 512, 500, 2><<<2048, 256, 0, stream>>>(h1, W2b, b2, h2);
    gemm3_kernel<<<1024, 256, 0, stream>>>(h2, W3b, b3, out);
  }
}